// Round 1
// 209.399 us; speedup vs baseline: 1.0398x; 1.0398x over previous
//
#include <hip/hip_runtime.h>
#include <hip/hip_bf16.h>

typedef unsigned short u16;
typedef __bf16 bf16x8 __attribute__((ext_vector_type(8)));
typedef float f32x4 __attribute__((ext_vector_type(4)));
typedef unsigned short u16x8 __attribute__((ext_vector_type(8)));
typedef unsigned short u16x4 __attribute__((ext_vector_type(4)));

__device__ __forceinline__ float bf2f(u16 u) {
  unsigned x = ((unsigned)u) << 16;
  return __builtin_bit_cast(float, x);
}
__device__ __forceinline__ u16 f2bf(float f) {
  unsigned u = __builtin_bit_cast(unsigned, f);
  u += 0x7fffu + ((u >> 16) & 1u);
  return (u16)(u >> 16);
}

// async global -> LDS, 16B per lane; lds base wave-uniform, HW scatters base+lane*16.
__device__ __forceinline__ void gload16(const u16* g, u16* lds) {
  __builtin_amdgcn_global_load_lds(
      (const __attribute__((address_space(1))) void*)g,
      (__attribute__((address_space(3))) void*)lds,
      16, 0, 0);
}

__device__ __forceinline__ void bar() {
  __builtin_amdgcn_sched_barrier(0);
  __builtin_amdgcn_s_barrier();
  __builtin_amdgcn_sched_barrier(0);
}
template <int N> __device__ __forceinline__ void wait_vm() {
  asm volatile("s_waitcnt vmcnt(%0)" :: "n"(N) : "memory");
  __builtin_amdgcn_sched_barrier(0);
}
__device__ __forceinline__ void wait_lgkm0() {
  asm volatile("s_waitcnt lgkmcnt(0)" ::: "memory");
  __builtin_amdgcn_sched_barrier(0);
}

// =========================================================================
// 256x256 8-phase bf16 GEMM  (T2 swizzle + T3/T4 counted vmcnt + T5 setprio)
// C[M,N] = A[M,K] * B[N,K]^T * cscale, bf16 out.
// 512 threads = 8 waves (2M x 4N); per-wave out 128x64 = 8x4 frags 16x16.
// K-tile = 64, split in 2 k-halves; stage unit = {A|B} x k-half = 256x32
// (16KB, 2 gload16/thread).  LDS 128KB: A[d][h] @ (d*2+h)*8192,
// B[d][h] @ 32768 + (d*2+h)*8192 (u16 elems), d = tile&1.
// Swizzle: 16B slot within (row,chunk q): slot = row*4 + (q ^ ((row^(row>>2))&3))
// -> each 16-lane fr-group covers all 8 bank-quads twice (conflict-free, same
// level as the verified 128-tile kernel).  Same per-lane global k-chunk
// contract as the verified kernel (k = kt + h*32 + q*8, q = lane>>4).
// Schedule per K-tile s (phases = (khalf, mhalf)):
//   p0: ds A(d,0) mh0 + B(d,0); stage Ak1(s+1)                     ; MFMA acc[0..3]
//   p1: ds A(d,0) mh1;          stage Bk1(s+1); vmcnt(8)           ; MFMA acc[4..7]
//   p2: ds A(d,1) mh0 + B(d,1); stage Ak0(s+2)                     ; MFMA acc[0..3]
//   p3: ds A(d,1) mh1;          stage Bk0(s+2); vmcnt(8)           ; MFMA acc[4..7]
// vmcnt(8) = 4 units in flight; in-order retirement guarantees the 2 units
// needed by the next k-half are landed.  Tail peels: (8,4) then (0,skip).
// =========================================================================
#define OFF_A(d,h) (((d)*2+(h))*8192)
#define OFF_B(d,h) (32768 + ((d)*2+(h))*8192)

struct G256 {
  const u16 *gA0, *gA1, *gB0, *gB1;  // per-lane staging src (k=0)
  int dst0, dst1;                    // LDS elem offsets within a unit
  int aoff0[4], aoff1[4], boff[4];   // frag LDS elem offsets within (d,h) region
  u16* lds;
};

__device__ __forceinline__ int swz_slot(int row, int q) {
  return row * 4 + (q ^ ((row ^ (row >> 2)) & 3));
}

__device__ __forceinline__ void mfma_quad(f32x4 (*accr)[4], const bf16x8* af, const bf16x8* bf) {
#pragma unroll
  for (int i = 0; i < 4; ++i)
#pragma unroll
    for (int j = 0; j < 4; ++j)
      accr[i][j] = __builtin_amdgcn_mfma_f32_16x16x32_bf16(af[i], bf[j], accr[i][j], 0, 0, 0);
}

template <int W1, int W3, bool S01, bool S23>
__device__ __forceinline__ void ktile256(const G256& g, int s, f32x4 (&acc)[8][4]) {
  const int d = s & 1;
  bf16x8 af[4], bf[4];
  const int kA1 = (s + 1) * 64 + 32;   // next tile, k-half 1
  const int kA0 = (s + 2) * 64;        // tile after next, k-half 0

  // ---- phase 0: khalf0, mhalf0 ----
#pragma unroll
  for (int i = 0; i < 4; ++i) af[i] = *(const bf16x8*)(g.lds + OFF_A(d, 0) + g.aoff0[i]);
#pragma unroll
  for (int j = 0; j < 4; ++j) bf[j] = *(const bf16x8*)(g.lds + OFF_B(d, 0) + g.boff[j]);
  if (S01) {
    gload16(g.gA0 + kA1, g.lds + OFF_A(d ^ 1, 1) + g.dst0);
    gload16(g.gA1 + kA1, g.lds + OFF_A(d ^ 1, 1) + g.dst1);
  }
  bar();
  wait_lgkm0();
  __builtin_amdgcn_s_setprio(1);
  mfma_quad(&acc[0], af, bf);
  __builtin_amdgcn_s_setprio(0);
  bar();

  // ---- phase 1: khalf0, mhalf1 (reuse bf) ----
#pragma unroll
  for (int i = 0; i < 4; ++i) af[i] = *(const bf16x8*)(g.lds + OFF_A(d, 0) + g.aoff1[i]);
  if (S01) {
    gload16(g.gB0 + kA1, g.lds + OFF_B(d ^ 1, 1) + g.dst0);
    gload16(g.gB1 + kA1, g.lds + OFF_B(d ^ 1, 1) + g.dst1);
  }
  wait_vm<W1>();
  bar();
  wait_lgkm0();
  __builtin_amdgcn_s_setprio(1);
  mfma_quad(&acc[4], af, bf);
  __builtin_amdgcn_s_setprio(0);
  bar();

  // ---- phase 2: khalf1, mhalf0 ----
#pragma unroll
  for (int i = 0; i < 4; ++i) af[i] = *(const bf16x8*)(g.lds + OFF_A(d, 1) + g.aoff0[i]);
#pragma unroll
  for (int j = 0; j < 4; ++j) bf[j] = *(const bf16x8*)(g.lds + OFF_B(d, 1) + g.boff[j]);
  if (S23) {
    gload16(g.gA0 + kA0, g.lds + OFF_A(d, 0) + g.dst0);
    gload16(g.gA1 + kA0, g.lds + OFF_A(d, 0) + g.dst1);
  }
  bar();
  wait_lgkm0();
  __builtin_amdgcn_s_setprio(1);
  mfma_quad(&acc[0], af, bf);
  __builtin_amdgcn_s_setprio(0);
  bar();

  // ---- phase 3: khalf1, mhalf1 ----
#pragma unroll
  for (int i = 0; i < 4; ++i) af[i] = *(const bf16x8*)(g.lds + OFF_A(d, 1) + g.aoff1[i]);
  if (S23) {
    gload16(g.gB0 + kA0, g.lds + OFF_B(d, 0) + g.dst0);
    gload16(g.gB1 + kA0, g.lds + OFF_B(d, 0) + g.dst1);
  }
  if constexpr (W3 >= 0) wait_vm<(W3 >= 0 ? W3 : 0)>();
  bar();
  wait_lgkm0();
  __builtin_amdgcn_s_setprio(1);
  mfma_quad(&acc[4], af, bf);
  __builtin_amdgcn_s_setprio(0);
  bar();
}

template <int NX, int NT>
__device__ __forceinline__ void gemm256_body(
    const u16* __restrict__ A, int lda, const u16* __restrict__ B, int ldb,
    u16* __restrict__ C, int ldc, float cscale, u16* lds, int bid)
{
  static_assert(NT >= 3, "tail peel needs NT>=3");
  const int by = (bid & 7) + 8 * (bid / (8 * NX));
  const int bx = (bid >> 3) % NX;
  const int m0 = by * 256, n0 = bx * 256;
  const int t = threadIdx.x;
  const int w = t >> 6, l = t & 63;
  const int wm = (w >> 2) * 128, wn = (w & 3) * 64;
  const int fr = l & 15, q = l >> 4;

  G256 g;
  g.lds = lds;
  // staging lane constants: round j slot = j*512 + w*64 + l
  {
    const int s0 = w * 64 + l;
    const int r0 = s0 >> 2, r1 = r0 + 128;
    const int q0 = (s0 & 3) ^ ((r0 ^ (r0 >> 2)) & 3);
    const int q1 = (s0 & 3) ^ ((r1 ^ (r1 >> 2)) & 3);
    g.gA0 = A + (size_t)(m0 + r0) * lda + q0 * 8;
    g.gA1 = A + (size_t)(m0 + r1) * lda + q1 * 8;
    g.gB0 = B + (size_t)(n0 + r0) * ldb + q0 * 8;
    g.gB1 = B + (size_t)(n0 + r1) * ldb + q1 * 8;
    g.dst0 = (w * 64) * 8;
    g.dst1 = (512 + w * 64) * 8;
  }
  // fragment lane constants
#pragma unroll
  for (int i = 0; i < 4; ++i) {
    g.aoff0[i] = swz_slot(wm + 16 * i + fr, q) * 8;
    g.aoff1[i] = swz_slot(wm + 64 + 16 * i + fr, q) * 8;
    g.boff[i]  = swz_slot(wn + 16 * i + fr, q) * 8;
  }

  f32x4 acc[8][4] = {};

  // prologue: 6 units (tile0 full, tile1 khalf0), then wait first 2 units
  gload16(g.gA0 + 0,  lds + OFF_A(0, 0) + g.dst0);
  gload16(g.gA1 + 0,  lds + OFF_A(0, 0) + g.dst1);
  gload16(g.gB0 + 0,  lds + OFF_B(0, 0) + g.dst0);
  gload16(g.gB1 + 0,  lds + OFF_B(0, 0) + g.dst1);
  gload16(g.gA0 + 32, lds + OFF_A(0, 1) + g.dst0);
  gload16(g.gA1 + 32, lds + OFF_A(0, 1) + g.dst1);
  gload16(g.gB0 + 32, lds + OFF_B(0, 1) + g.dst0);
  gload16(g.gB1 + 32, lds + OFF_B(0, 1) + g.dst1);
  gload16(g.gA0 + 64, lds + OFF_A(1, 0) + g.dst0);
  gload16(g.gA1 + 64, lds + OFF_A(1, 0) + g.dst1);
  gload16(g.gB0 + 64, lds + OFF_B(1, 0) + g.dst0);
  gload16(g.gB1 + 64, lds + OFF_B(1, 0) + g.dst1);
  wait_vm<8>();
  bar();

  for (int s = 0; s + 2 < NT; ++s)
    ktile256<8, 8, true, true>(g, s, acc);
  ktile256<8, 4, true, false>(g, NT - 2, acc);
  ktile256<0, -1, false, false>(g, NT - 1, acc);

  // ---- epilogue: per-wave LDS round-trip (two 64-row halves), 16B stores ----
  // C/D layout (m89): col = lane&15, row = (lane>>4)*4 + reg
  const int er = q * 4, ec = fr;
  const int rg = l >> 3, c = l & 7;
  u16* eb = lds + w * 4608;                // 64 rows x 72 u16 per wave
#pragma unroll
  for (int half = 0; half < 2; ++half) {
#pragma unroll
    for (int i = 0; i < 4; ++i)
#pragma unroll
      for (int j = 0; j < 4; ++j)
#pragma unroll
        for (int r = 0; r < 4; ++r)
          eb[(16 * i + er + r) * 72 + 16 * j + ec] = f2bf(acc[4 * half + i][j][r] * cscale);
#pragma unroll
    for (int k = 0; k < 8; ++k) {
      const int row = k * 8 + rg;
      u16x8 v = *(const u16x8*)(eb + row * 72 + c * 8);
      *(u16x8*)(C + (size_t)(m0 + wm + 64 * half + row) * ldc + n0 + wn + c * 8) = v;
    }
  }
}

// stage 1: QKV = E @ Wt^T  [4096 x 3072], K=1024.  grid 192 (16x12), 1 blk/CU.
__global__ __launch_bounds__(512, 2) void gemm_qkv256(const u16* __restrict__ A,
                                                      const u16* __restrict__ B,
                                                      u16* __restrict__ C) {
  __shared__ __align__(16) u16 lds[65536];   // 128 KiB
  gemm256_body<12, 16>(A, 1024, B, 1024, C, 3072, 1.0f, lds, blockIdx.x);
}

// stage 2: S = (Q @ K^T)/32  [4096 x 4096], K=1024.  grid 256 (16x16).
__global__ __launch_bounds__(512, 2) void gemm_score256(const u16* __restrict__ QKV,
                                                        u16* __restrict__ S) {
  __shared__ __align__(16) u16 lds[65536];
  gemm256_body<16, 16>(QKV, 3072, QKV + 1024, 3072, S, 4096, 0.03125f, lds, blockIdx.x);
}

// =========================================================================
// legacy 128xBN 2-barrier GEMM body — kept for PV (N=1024 makes 256² tiles
// underfill the grid: 64 blocks / 256 CUs).  Unchanged from the verified
// kernel; see session notes R2/R4/R6/R7/R11/R12.
// =========================================================================
template <int OUT_MODE, int NX, int BK, int BN>
__device__ __forceinline__ void gemm_body(
    const u16* __restrict__ A, int lda,
    const u16* __restrict__ B, int ldb,
    void* __restrict__ C, int ldc, int kt0, int Kc, float cscale,
    u16* lds, int bid)
{
  u16* As = lds;
  u16* Bs = lds + 128 * BK;

  constexpr int CPR = BK / 8;
  constexpr int RPG = 512 / BK;
  constexpr int IPA = 32 / RPG;
  constexpr int IPB = (BN / 4) / RPG;
  constexpr int NWN = BN / 32;

  const int by = (bid & 7) + 8 * (bid / (8 * NX));
  const int bx = (bid >> 3) % NX;
  const int m0 = by * 128, n0 = bx * BN;

  const int t = threadIdx.x;
  const int w = t >> 6, l = t & 63;
  const int srow = l / CPR;
  const int lc = l % CPR;
  const int wm = (w >> 1) * 64;
  const int wn = (w & 1) * (BN / 2);
  const int fr = l & 15;
  const int q = l >> 4;

  f32x4 acc[4][NWN] = {};

  for (int kk = 0; kk < Kc; kk += BK) {
    const int kt = kt0 + kk;
    __syncthreads();
#pragma unroll
    for (int j = 0; j < IPA; ++j) {
      const int rr = RPG * (IPA * w + j);
      const int ga = rr + srow;
      const int sch = ((lc ^ (ga & 7))) * 8;
      gload16(A + (size_t)(m0 + ga) * lda + kt + sch, As + rr * BK);
    }
#pragma unroll
    for (int j = 0; j < IPB; ++j) {
      const int rr = RPG * (IPB * w + j);
      const int gb = rr + srow;
      const int sch = ((lc ^ (gb & 7))) * 8;
      gload16(B + (size_t)(n0 + gb) * ldb + kt + sch, Bs + rr * BK);
    }
    __syncthreads();

#pragma unroll
    for (int s = 0; s < BK / 32; ++s) {
      const int j = s * 4 + q;
      bf16x8 af[4], bfr[NWN];
#pragma unroll
      for (int i = 0; i < 4; ++i) {
        const int ra = wm + 16 * i + fr;
        af[i] = *(const bf16x8*)(As + ra * BK + (j ^ (ra & 7)) * 8);
      }
#pragma unroll
      for (int i = 0; i < NWN; ++i) {
        const int rb = wn + 16 * i + fr;
        bfr[i] = *(const bf16x8*)(Bs + rb * BK + (j ^ (rb & 7)) * 8);
      }
#pragma unroll
      for (int i = 0; i < 4; ++i)
#pragma unroll
        for (int jj = 0; jj < NWN; ++jj)
          acc[i][jj] = __builtin_amdgcn_mfma_f32_16x16x32_bf16(af[i], bfr[jj], acc[i][jj], 0, 0, 0);
    }
  }

  __syncthreads();
  const int er = q * 4;
  const int ec = l & 15;
  const int g = l >> 3, c = l & 7;

  if (OUT_MODE == 1) {
    u16* eb = lds + w * 4608;
#pragma unroll
    for (int i = 0; i < 4; ++i)
#pragma unroll
      for (int jj = 0; jj < NWN; ++jj)
#pragma unroll
        for (int r = 0; r < 4; ++r)
          eb[(16 * i + er + r) * 72 + 16 * jj + ec] = f2bf(acc[i][jj][r] * cscale);
#pragma unroll
    for (int k = 0; k < 8; ++k) {
      const int row = k * 8 + g;
      u16x8 v = *(const u16x8*)(eb + row * 72 + c * 8);
      *(u16x8*)((u16*)C + (size_t)(m0 + wm + row) * ldc + n0 + wn + c * 8) = v;
    }
  } else {
    float* eb = (float*)lds + w * 2560;
#pragma unroll
    for (int i = 0; i < 4; ++i)
#pragma unroll
      for (int jj = 0; jj < NWN; ++jj)
#pragma unroll
        for (int r = 0; r < 4; ++r)
          eb[(16 * i + er + r) * 40 + 16 * jj + ec] = acc[i][jj][r];
#pragma unroll
    for (int k = 0; k < 8; ++k) {
      const int row = k * 8 + g;
      float4 v = *(const float4*)(eb + row * 40 + c * 4);
      *(float4*)((float*)C + (size_t)(m0 + wm + row) * ldc + n0 + wn + c * 4) = v;
    }
  }
}

// stage 4: Out = P @ Vt^T  [4096 x 1024], K=4096, BK=128, 128x64 tiles.
__global__ __launch_bounds__(256) void gemm_pv(const u16* __restrict__ S,
                                               const u16* __restrict__ Vt,
                                               float* __restrict__ O) {
  __shared__ __align__(16) u16 lds[24576];
  gemm_body<0, 16, 128, 64>(S, 4096, Vt, 4096, O, 1024, 0, 4096,
                            1.0f, lds, blockIdx.x);
}

// -------------------------------------------------------------------------
// stage 0 merged: blocks 0..4095 = E f32->bf16 cast; 4096..7167 = W transposes.
// -------------------------------------------------------------------------
__global__ __launch_bounds__(256) void prep(
    const float* __restrict__ E,
    const float* __restrict__ w0, const float* __restrict__ w1,
    const float* __restrict__ w2,
    u16* __restrict__ Ebf, u16* __restrict__ Wt)
{
  int b = blockIdx.x;
  if (b < 4096) {
    const int i = (b * 256 + threadIdx.x) * 4;
    float4 f = *(const float4*)(E + i);
    u16x4 o;
    o.x = f2bf(f.x); o.y = f2bf(f.y); o.z = f2bf(f.z); o.w = f2bf(f.w);
    *(u16x4*)(Ebf + i) = o;
  } else {
    b -= 4096;
    const int which = b >> 10;
    const int tile = b & 1023;
    const float* in = (which == 0) ? w0 : (which == 1) ? w1 : w2;
    u16* o = Wt + (size_t)which * 1024 * 1024;
    const int c0 = (tile & 31) * 32, r0 = (tile >> 5) * 32;
    __shared__ u16 tl[32][33];
    const int tx = threadIdx.x & 31, ty0 = threadIdx.x >> 5;
#pragma unroll
    for (int k = 0; k < 4; ++k) {
      const int ty = ty0 + k * 8;
      tl[ty][tx] = f2bf(in[(size_t)(r0 + ty) * 1024 + c0 + tx]);
    }
    __syncthreads();
#pragma unroll
    for (int k = 0; k < 4; ++k) {
      const int ty = ty0 + k * 8;
      o[(size_t)(c0 + ty) * 1024 + r0 + tx] = tl[tx][ty];
    }
  }
}

// -------------------------------------------------------------------------
// stage 3 merged: blocks 0..4095 = row softmax (in-place, bf16 S, scale
// pre-applied); blocks 4096..8191 = V transpose (32x32 tiles) — moved here
// from the score dispatch (both memory-bound; they overlap).
// -------------------------------------------------------------------------
__global__ __launch_bounds__(256) void softmax_tv(u16* __restrict__ S,
                                                  const u16* __restrict__ QKV,
                                                  u16* __restrict__ Vt) {
  __shared__ float red[8];
  __shared__ u16 tl[32][33];
  const int b = blockIdx.x;
  if (b < 4096) {
    const int N = 4096;
    u16* p = S + (size_t)b * N;
    const int t = threadIdx.x;
    u16x8 u0 = ((const u16x8*)p)[t * 2];
    u16x8 u1 = ((const u16x8*)p)[t * 2 + 1];
    float v[16];
#pragma unroll
    for (int i = 0; i < 8; ++i) v[i] = bf2f(u0[i]);
#pragma unroll
    for (int i = 0; i < 8; ++i) v[8 + i] = bf2f(u1[i]);

    float m = -1e30f;
#pragma unroll
    for (int i = 0; i < 16; ++i) m = fmaxf(m, v[i]);
#pragma unroll
    for (int off = 32; off; off >>= 1) m = fmaxf(m, __shfl_xor(m, off));
    if ((t & 63) == 0) red[t >> 6] = m;
    __syncthreads();
    m = fmaxf(fmaxf(red[0], red[1]), fmaxf(red[2], red[3]));

    float s = 0.f;
#pragma unroll
    for (int i = 0; i < 16; ++i) { v[i] = __expf(v[i] - m); s += v[i]; }
#pragma unroll
    for (int off = 32; off; off >>= 1) s += __shfl_xor(s, off);
    if ((t & 63) == 0) red[4 + (t >> 6)] = s;
    __syncthreads();
    s = (red[4] + red[5]) + (red[6] + red[7]);
    const float inv = 1.0f / s;

    u16x8 o0, o1;
#pragma unroll
    for (int i = 0; i < 8; ++i) o0[i] = f2bf(v[i] * inv);
#pragma unroll
    for (int i = 0; i < 8; ++i) o1[i] = f2bf(v[8 + i] * inv);
    ((u16x8*)p)[t * 2] = o0;
    ((u16x8*)p)[t * 2 + 1] = o1;
  } else {
    const int v = b - 4096;                       // 0..4095
    const int c0 = (v & 31) * 32;                 // V col 0..1023
    const int r0 = (v >> 5) * 32;                 // V row 0..4095
    const int tx = threadIdx.x & 31, ty0 = threadIdx.x >> 5;
    const u16* Vin = QKV + 2048;                  // V cols of QKV (ld 3072)
#pragma unroll
    for (int k = 0; k < 4; ++k) {
      const int ty = ty0 + k * 8;
      tl[ty][tx] = Vin[(size_t)(r0 + ty) * 3072 + c0 + tx];
    }
    __syncthreads();
#pragma unroll
    for (int k = 0; k < 4; ++k) {
      const int ty = ty0 + k * 8;
      Vt[(size_t)(c0 + ty) * 4096 + r0 + tx] = tl[tx][ty];
    }
  }
}

// -------------------------------------------------------------------------
// S=4096, D_IN=1024, D_OUT=1024.  fp32 in, fp32 out.
// ws layout (bytes): Ebf 8MB | Wt 6MB | QKV 24MB | Vt 8MB | S 32MB = 78MB
// 5 dispatches: prep -> qkv(8phase) -> score(8phase) -> softmax+tV -> pv.
// -------------------------------------------------------------------------
extern "C" void kernel_launch(void* const* d_in, const int* in_sizes, int n_in,
                              void* d_out, int out_size, void* d_ws, size_t ws_size,
                              hipStream_t stream) {
  const float* E  = (const float*)d_in[0];
  const float* Wq = (const float*)d_in[1];
  const float* Wk = (const float*)d_in[2];
  const float* Wv = (const float*)d_in[3];
  float* Out = (float*)d_out;

  char* w = (char*)d_ws;
  u16* Ebf = (u16*)(w);
  u16* Wt  = (u16*)(w + (size_t)(8u << 20));
  u16* QKV = (u16*)(w + (size_t)(14u << 20));
  u16* Vt  = (u16*)(w + (size_t)(38u << 20));
  u16* S   = (u16*)(w + (size_t)(46u << 20));

  // stage 0: E cast + W transposes
  prep<<<7168, 256, 0, stream>>>(E, Wq, Wk, Wv, Ebf, Wt);

  // stage 1: QKV = E @ Wt^T   [4096 x 3072], K=1024  (8-phase 256² tiles)
  gemm_qkv256<<<192, 512, 0, stream>>>(Ebf, Wt, QKV);

  // stage 2: S = (Q @ K^T) / 32  (8-phase 256² tiles)
  gemm_score256<<<256, 512, 0, stream>>>(QKV, S);

  // stage 3: P = softmax(S) in place  +  V^T
  softmax_tv<<<8192, 256, 0, stream>>>(S, QKV, Vt);

  // stage 4: Out = P @ Vt^T, 128x64 tiles, no split-K
  gemm_pv<<<512, 256, 0, stream>>>(S, Vt, Out);
}